// Round 12
// baseline (370.870 us; speedup 1.0000x reference)
//
#include <hip/hip_runtime.h>
#include <hip/hip_bf16.h>

#define N_NODES 100000
#define N_EDGES 1600000
#define D 128
#define NB 1563            // ceil(100000/64) buckets of 64 nodes
#define PB 128             // partition blocks
#define CHUNK 12500        // PB*CHUNK == N_EDGES
#define SENT N_NODES       // sentinel (zero) row index
#define BREG 2560          // fixed pairD/srcS region per bucket (mean 1024, sigma 32 -> 48 sigma)
#define EREG 2816          // fixed esrc region per bucket (max padded total 2560+192=2752 < 2816)
#define BCAP 2816          // LDS staging capacity per bucket in k_prep sort

typedef __attribute__((ext_vector_type(8))) short bf16x8;
typedef __attribute__((ext_vector_type(4))) float f32x4;

__device__ __forceinline__ float bf2f(unsigned short u) {
    unsigned int x = ((unsigned int)u) << 16;
    return __builtin_bit_cast(float, x);
}
__device__ __forceinline__ unsigned short f2bf(float f) {
    unsigned int x = __builtin_bit_cast(unsigned int, f);
    x += 0x7fffu + ((x >> 16) & 1u);   // round-to-nearest-even
    return (unsigned short)(x >> 16);
}
__device__ __forceinline__ void accum8(float* acc, uint4 x) {
    acc[0] += bf2f((unsigned short)x.x); acc[1] += bf2f((unsigned short)(x.x >> 16));
    acc[2] += bf2f((unsigned short)x.y); acc[3] += bf2f((unsigned short)(x.y >> 16));
    acc[4] += bf2f((unsigned short)x.z); acc[5] += bf2f((unsigned short)(x.z >> 16));
    acc[6] += bf2f((unsigned short)x.w); acc[7] += bf2f((unsigned short)(x.w >> 16));
}

// ---- zero the per-bucket reservation counters (replaces hipMemsetAsync: no runtime API
//      inside kernel_launch -> no graph-capture risk) ----
__global__ void k_zero(int* __restrict__ g, int n) {
    int i = blockIdx.x * 256 + threadIdx.x;
    if (i < n) g[i] = 0;
}

// ---- single-pass partition: LDS histogram -> per-(bucket,block) range reservation via
//      ONE global atomic each (LDS-pre-aggregated, G12 pattern) -> LDS-cursor scatter into
//      fixed bucket regions. Replaces pcount + 2 scan kernels + pscatter. ----
__global__ __launch_bounds__(1024) void k_pscatter2(const int* __restrict__ src, const int* __restrict__ dst,
                                                    int* __restrict__ gcntD, int* __restrict__ gcntS,
                                                    unsigned int* __restrict__ pairD, unsigned char* __restrict__ srcS) {
    __shared__ int hd[NB];
    __shared__ int hs[NB];
    int t = threadIdx.x, blk = blockIdx.x;
    for (int i = t; i < NB; i += 1024) { hd[i] = 0; hs[i] = 0; }
    __syncthreads();
    int base = blk * CHUNK;
    // pass 1: count (chunk lands in L2 for pass 2)
    for (int i = t; i < CHUNK; i += 1024) {
        int e = base + i;
        atomicAdd(&hd[dst[e] >> 6], 1);
        atomicAdd(&hs[src[e] >> 6], 1);
    }
    __syncthreads();
    // reserve a contiguous range per touched bucket; LDS cell becomes the write cursor
    for (int i = t; i < NB; i += 1024) {
        int c = hd[i];
        hd[i] = c ? atomicAdd(&gcntD[i], c) : 0;
        c = hs[i];
        hs[i] = c ? atomicAdd(&gcntS[i], c) : 0;
    }
    __syncthreads();
    // pass 2: scatter into fixed bucket regions
    for (int i = t; i < CHUNK; i += 1024) {
        int e = base + i;
        int s = src[e], d = dst[e];
        int pd = atomicAdd(&hd[d >> 6], 1);
        if (pd < BREG) pairD[(size_t)(d >> 6) * BREG + pd] = ((unsigned int)(d & 63) << 26) | (unsigned int)s;
        int ps = atomicAdd(&hs[s >> 6], 1);
        if (ps < BREG) srcS[(size_t)(s >> 6) * BREG + ps] = (unsigned char)(s & 63);
    }
}

// ---- merged prep (per bucket b): out-degree->norm_src, cvt own 64 x-rows -> hA,
//      counting sort -> padded CSR (fixed esrc regions); blocks 0..23 transpose W;
//      block 0 zeroes SENT rows ----
__global__ __launch_bounds__(256) void k_prep(
        const unsigned int* __restrict__ pairD, const unsigned char* __restrict__ srcS,
        const int* __restrict__ gcntD, const int* __restrict__ gcntS,
        const float* __restrict__ x,
        const float* __restrict__ W0, const float* __restrict__ W1, const float* __restrict__ W2,
        int* __restrict__ esrc, int* __restrict__ rowbeg, int* __restrict__ degD,
        float* __restrict__ norm_src, unsigned short* __restrict__ Wt,
        unsigned short* __restrict__ hA, unsigned short* __restrict__ hB) {
    __shared__ int c[64];
    __shared__ float nsl[64];
    __shared__ int cnt[64], off[64], cur[64];
    __shared__ int ptotS;
    __shared__ int stage[BCAP];
    int b = blockIdx.x, t = threadIdx.x;
    int lane = t & 63, wave = t >> 6;

    // --- weight transpose (blocks 0..23 cover 3 layers x 2048 groups of 8) ---
    if (b < 24) {
        int gid = b * 256 + t;
        int layer = gid >> 11;
        int di8   = gid & 2047;
        const float* W = (layer == 0) ? W0 : ((layer == 1) ? W1 : W2);
        int di   = di8 * 8;
        int wl   = di8 & 63;
        int nt   = (di8 >> 6) & 7;
        int kc   = di8 >> 9;
        int quad = wl >> 4, wcol = wl & 15;
        unsigned short v[8];
#pragma unroll
        for (int j = 0; j < 8; j++) {
            int k = kc * 32 + quad * 8 + j;
            v[j] = f2bf(W[k * 128 + nt * 16 + wcol]);
        }
        unsigned short* dp = Wt + (size_t)layer * 16384 + di;
#pragma unroll
        for (int j = 0; j < 8; j++) dp[j] = v[j];
    }
    // --- sentinel rows of hA/hB (block 0); sentinel offset 25.6MB is beyond aliased buffers ---
    if (b == 0 && t < 32) {
        uint4 z = {0u, 0u, 0u, 0u};
        if (t < 16) ((uint4*)(hA + (size_t)SENT * D))[t] = z;
        else        ((uint4*)(hB + (size_t)SENT * D))[t - 16] = z;
    }

    // --- phase 1: out-degree histogram -> norm_src (this bucket's 64 src nodes) ---
    if (t < 64) c[t] = 0;
    __syncthreads();
    int nS = gcntS[b]; if (nS > BREG) nS = BREG;
    int begS = b * BREG;
    for (int i = t; i < nS; i += 256) atomicAdd(&c[srcS[begS + i]], 1);
    __syncthreads();
    if (t < 64) {
        int g = b * 64 + t;
        float nv = 1.f;
        if (g < N_NODES) {
            int a = c[t]; if (a < 1) a = 1;
            nv = rsqrtf((float)a);
            norm_src[g] = nv;
        }
        nsl[t] = nv;
    }
    __syncthreads();

    // --- phase 2: cvt this bucket's 64 rows of x (fp32) -> hA (bf16, pre-scaled) ---
    for (int i = t; i < 2048; i += 256) {       // 64 rows x 32 float4
        int row = b * 64 + (i >> 5);
        if (row < N_NODES) {
            float sc = nsl[i >> 5];
            const float4 v = ((const float4*)x)[(size_t)row * 32 + (i & 31)];
            unsigned int lo = (unsigned int)f2bf(v.x * sc) | ((unsigned int)f2bf(v.y * sc) << 16);
            unsigned int hi = (unsigned int)f2bf(v.z * sc) | ((unsigned int)f2bf(v.w * sc) << 16);
            ((uint2*)hA)[(size_t)row * 32 + (i & 31)] = make_uint2(lo, hi);
        }
    }

    // --- phase 3: per-bucket counting sort -> padded CSR (pad-4, sentinel-filled) ---
    if (t < 64) cnt[t] = 0;
    __syncthreads();
    int n = gcntD[b]; if (n > BREG) n = BREG;
    int beg = b * BREG;
    int base = b * EREG;        // fixed esrc region for this bucket
    for (int i = t; i < n; i += 256) atomicAdd(&cnt[pairD[beg + i] >> 26], 1);
    __syncthreads();
    if (wave == 0) {
        int v = cnt[lane];
        int pc = (v + 3) & ~3;            // pad each row to multiple of 4
        int xx = pc;
        for (int o = 1; o < 64; o <<= 1) { int y = __shfl_up(xx, o); if (lane >= o) xx += y; }
        off[lane] = xx - pc;
        cur[lane] = xx - pc;
        if (lane == 63) ptotS = xx;       // padded total for this bucket
    }
    __syncthreads();
    int ptot = ptotS; if (ptot > BCAP) ptot = BCAP;
    if (t < 64) {
        int g = b * 64 + t;
        if (g < N_NODES) { rowbeg[g] = base + off[t]; degD[g] = cnt[t]; }
    }
    for (int i = t; i < ptot; i += 256) stage[i] = SENT;   // sentinel pre-fill
    __syncthreads();
    for (int i = t; i < n; i += 256) {
        unsigned int p = pairD[beg + i];
        int pos = atomicAdd(&cur[p >> 26], 1);
        if (pos < BCAP) stage[pos] = (int)(p & 0x3FFFFFFu);
    }
    __syncthreads();
    for (int i = t; i < ptot; i += 256) esrc[base + i] = stage[i];   // coalesced write-out
}

// swizzled A-tile byte address: row-major [64][128] bf16, 16B blocks XOR'd by (row&7)
__device__ __forceinline__ int aswz(int row, int byte16) {
    return row * 256 + (byte16 ^ ((row & 7) << 4));
}

// ---- fused layer: reg-window gather (1-hop chain via shfl-staged indices) -> LDS A-tile ----
// BYTE-IDENTICAL to round-8 control (72.4 us; 16.9KB LDS, 8 blocks/CU; demand-bound at ~6.4 TB/s).
__global__ __launch_bounds__(256, 8) void k_fused(const unsigned short* __restrict__ hin,
        const int* __restrict__ esrc, const int* __restrict__ rowbeg, const int* __restrict__ degD,
        const float* __restrict__ nsp,
        const unsigned short* __restrict__ Wt, const float* __restrict__ bias,
        unsigned short* __restrict__ Cb, float* __restrict__ Cf, int M) {
    __shared__ int rb[64];
    __shared__ int dgt[64];
    __shared__ unsigned short lA[64 * 128];
    int b = blockIdx.x, t = threadIdx.x;
    int lane = t & 63, wave = t >> 6;          // wave 0..3
    int sub = lane >> 4, col = lane & 15;

    if (t < 64) {
        int g = b * 64 + t;
        rb[t]  = (g < M) ? rowbeg[g] : 0;
        dgt[t] = (g < M) ? degD[g] : 0;
    }
    __syncthreads();

    // ---- phase A: wave-per-row gather (padded to x4, sentinel row = zeros) ----
    for (int r = wave; r < 64; r += 4) {
        int ro = rb[r];
        int dgr = dgt[r];
        int re = ro + ((dgr + 3) & ~3);
        float acc[8];
#pragma unroll
        for (int j = 0; j < 8; j++) acc[j] = 0.f;
        int e = ro;
        while (e < re) {
            int w = e;                                   // 64-edge register window
            int wl = w + lane;
            int idxreg = (wl < re) ? esrc[wl] : 0;       // coalesced, exec-masked
            int wend = (w + 64 < re) ? (w + 64) : re;
            // main: 16 edges/iter, 4 uint4 in flight, indices via shfl (no global dep)
            for (; e + 16 <= wend; e += 16) {
                int q = e - w;
                int s0 = __shfl(idxreg, q + sub);
                int s1 = __shfl(idxreg, q + 4 + sub);
                int s2 = __shfl(idxreg, q + 8 + sub);
                int s3 = __shfl(idxreg, q + 12 + sub);
                uint4 x0 = *(const uint4*)(hin + (size_t)s0 * D + col * 8);
                uint4 x1 = *(const uint4*)(hin + (size_t)s1 * D + col * 8);
                uint4 x2 = *(const uint4*)(hin + (size_t)s2 * D + col * 8);
                uint4 x3 = *(const uint4*)(hin + (size_t)s3 * D + col * 8);
                accum8(acc, x0); accum8(acc, x1); accum8(acc, x2); accum8(acc, x3);
            }
            // tail: <=3 groups of 4 edges (wave-uniform trip count)
            for (; e < wend; e += 4) {
                int q = e - w;
                int s = __shfl(idxreg, q + sub);
                uint4 x = *(const uint4*)(hin + (size_t)s * D + col * 8);
                accum8(acc, x);
            }
        }
#pragma unroll
        for (int j = 0; j < 8; j++) {
            acc[j] += __shfl_xor(acc[j], 16);
            acc[j] += __shfl_xor(acc[j], 32);
        }
        if (sub == 0) {
            int d2 = dgr; if (d2 < 1) d2 = 1;
            float s = rsqrtf((float)d2);
            uint4 o;
            o.x = (unsigned int)f2bf(acc[0] * s) | ((unsigned int)f2bf(acc[1] * s) << 16);
            o.y = (unsigned int)f2bf(acc[2] * s) | ((unsigned int)f2bf(acc[3] * s) << 16);
            o.z = (unsigned int)f2bf(acc[4] * s) | ((unsigned int)f2bf(acc[5] * s) << 16);
            o.w = (unsigned int)f2bf(acc[6] * s) | ((unsigned int)f2bf(acc[7] * s) << 16);
            *(uint4*)((char*)lA + aswz(r, col * 16)) = o;
        }
    }
    __syncthreads();

    // ---- phase B: MFMA GEMM; 4 waves = 4 row-tiles; 2 N-half passes keep VGPR <= 64 ----
    int row0 = b * 64 + wave * 16;
    float nsv[4];
    if (Cb) {
#pragma unroll
        for (int r = 0; r < 4; r++) {
            int rr = row0 + sub * 4 + r;
            nsv[r] = (rr < M) ? nsp[rr] : 1.f;
        }
    }
#pragma unroll
    for (int half = 0; half < 2; half++) {
        f32x4 acc2[4];
#pragma unroll
        for (int i = 0; i < 4; i++) acc2[i] = (f32x4){0.f, 0.f, 0.f, 0.f};
        int lr = wave * 16 + col;
#pragma unroll
        for (int kc = 0; kc < 4; kc++) {
            bf16x8 af = *(const bf16x8*)((const char*)lA + aswz(lr, kc * 64 + sub * 16));
#pragma unroll
            for (int j = 0; j < 4; j++) {
                int nt = half * 4 + j;
                bf16x8 bfr = *(const bf16x8*)(Wt + ((size_t)(kc * 8 + nt) * 64 + lane) * 8);
                acc2[j] = __builtin_amdgcn_mfma_f32_16x16x32_bf16(af, bfr, acc2[j], 0, 0, 0);
            }
        }
#pragma unroll
        for (int j = 0; j < 4; j++) {
            int nt = half * 4 + j;
            float bv = bias[nt * 16 + col];
#pragma unroll
            for (int r = 0; r < 4; r++) {
                int rr = row0 + sub * 4 + r;
                if (rr < M) {
                    float v = acc2[j][r] + bv;
                    if (Cf) {
                        Cf[(size_t)rr * D + nt * 16 + col] = v;
                    } else {
                        v = fmaxf(v, 0.f) * nsv[r];
                        Cb[(size_t)rr * D + nt * 16 + col] = f2bf(v);
                    }
                }
            }
        }
    }
}

extern "C" void kernel_launch(void* const* d_in, const int* in_sizes, int n_in,
                              void* d_out, int out_size, void* d_ws, size_t ws_size,
                              hipStream_t stream) {
    const float* x  = (const float*)d_in[0];
    const int* src = (const int*)d_in[1];
    const int* dst = (const int*)d_in[2];
    const float* Wl[3] = {(const float*)d_in[3], (const float*)d_in[5], (const float*)d_in[7]};
    const float* Bl[3] = {(const float*)d_in[4], (const float*)d_in[6], (const float*)d_in[8]};

    const int N = N_NODES;
    const int Mpad = ((N + 63) / 64) * 64;   // 100032 rows (includes SENT row)
    const size_t HBYTES = (size_t)Mpad * D * 2;  // 25,608,192

    char* ws = (char*)d_ws;

    // ---- aliased region: hB overlays preprocessing buffers that die before layer 0 writes hB ----
    unsigned short* hB = (unsigned short*)ws;                 // [0, HBYTES)
    unsigned int*  pairD = (unsigned int*)ws;                                // 16.0 MB (NB*BREG*4)
    unsigned char* srcS  = (unsigned char*)(ws + (size_t)NB * BREG * 4);     // 4.0 MB  (NB*BREG)
    int* gcntD = (int*)(ws + (size_t)NB * BREG * 5);                         // 6.25 KB
    int* gcntS = gcntD + NB;                                                 // 6.25 KB
    // aliased use: ~20.02 MB < HBYTES ✓ (all dead after k_prep; hB sentinel row @25.6MB is beyond)

    // ---- persistent region after hB ----
    size_t o = HBYTES;
    auto take = [&](size_t bytes) -> void* {
        o = (o + 255) & ~(size_t)255;
        void* p = ws + o;
        o += bytes;
        return p;
    };
    float* norm_src = (float*)take((size_t)N * 4);
    int*   esrc     = (int*)take(((size_t)NB * EREG + 256) * 4);  // fixed regions + window slack
    int*   rowbeg   = (int*)take((size_t)N * 4);
    int*   degD     = (int*)take((size_t)N * 4);
    unsigned short* Wt = (unsigned short*)take((size_t)3 * 128 * 128 * 2);
    unsigned short* hA = (unsigned short*)take(HBYTES);

    // zero the per-bucket reservation counters (kernel, not hipMemsetAsync: graph-capture safe)
    k_zero<<<(2 * NB + 255) / 256, 256, 0, stream>>>(gcntD, 2 * NB);
    // single-pass partition: histogram -> range reservation -> scatter into fixed regions
    k_pscatter2<<<PB, 1024, 0, stream>>>(src, dst, gcntD, gcntS, pairD, srcS);
    // merged: norm_src + cvt + counting sort (fixed esrc regions) + weight transpose + sentinel zero
    k_prep<<<NB, 256, 0, stream>>>(pairD, srcS, gcntD, gcntS, x,
                                   Wl[0], Wl[1], Wl[2],
                                   esrc, rowbeg, degD, norm_src, Wt, hA, hB);

    // fused layers: gather + GEMM + activation(+prescale) per launch
    k_fused<<<NB, 256, 0, stream>>>(hA, esrc, rowbeg, degD, norm_src, Wt,         Bl[0], hB, nullptr, N);
    k_fused<<<NB, 256, 0, stream>>>(hB, esrc, rowbeg, degD, norm_src, Wt + 16384, Bl[1], hA, nullptr, N);
    k_fused<<<NB, 256, 0, stream>>>(hA, esrc, rowbeg, degD, norm_src, Wt + 32768, Bl[2], nullptr, (float*)d_out, N);
}